// Round 2
// baseline (58.432 us; speedup 1.0000x reference)
//
#include <hip/hip_runtime.h>

// ConvCapsules2d:
//  activations: [8,32,14,14] f32
//  poses:       [8,32,4,4,14,14] f32
//  W_ij:        [32,32,4,4,3,3] f32  (b,c,m,j,k,l)
// Outputs (concatenated flat):
//  acts_out: [8,32,1,1,1,6,6,3,3]            = 82944 f32
//  V_ji:     [8,32,32,16,1,6,6,3,3]          = 42467328 f32
// V[n,b,c,i,j,f,g,k,l] = sum_m poses[n,b,i,m,f*2+k,g*2+l] * W[b,c,m,j,k,l]
// patch flat index r = f*54 + g*9 + k*3 + l   (strides of [6,6,3,3])

#define RLEN 324          // F*F*K*K = 6*6*3*3
#define ACTS_OUT 82944    // 8*32*324

__global__ __launch_bounds__(256) void acts_kernel(const float* __restrict__ act,
                                                   float* __restrict__ out) {
    int a = blockIdx.x * 256 + threadIdx.x;        // < 82944 (=324*256 exactly)
    int nb = a / RLEN;
    int r  = a - nb * RLEN;
    int f  = r / 54;  int r1 = r - f * 54;
    int g  = r1 / 9;  int r2 = r1 - g * 9;
    int k  = r2 / 3;  int l  = r2 - k * 3;
    out[a] = act[nb * 196 + (f * 2 + k) * 14 + (g * 2 + l)];
}

__global__ __launch_bounds__(256) void v_kernel(const float* __restrict__ poses,
                                                const float* __restrict__ W,
                                                float* __restrict__ out) {
    __shared__ float Pl[3136];     // poses[n,b,:,:,:,:]  (i*4+m)*196 + h*14+w
    __shared__ float Wl[144];      // W[b,c,:,:,:,:]      m*36 + j*9 + k*3 + l
    __shared__ int   poseOff[RLEN];
    __shared__ int   wOff[RLEN];

    const int bid = blockIdx.x;    // n*1024 + b*32 + c
    const int c   = bid & 31;
    const int b   = (bid >> 5) & 31;
    const int nb  = bid >> 5;      // n*32 + b
    const int tid = threadIdx.x;

    // stage poses[n,b]: 3136 floats = 784 float4
    const float4* psrc = (const float4*)(poses + (size_t)nb * 3136);
    for (int i4 = tid; i4 < 784; i4 += 256)
        ((float4*)Pl)[i4] = psrc[i4];
    // stage W[b,c]: 144 floats = 36 float4
    const float4* wsrc = (const float4*)(W + (size_t)(b * 32 + c) * 144);
    if (tid < 36) ((float4*)Wl)[tid] = wsrc[tid];
    // decode tables: r = f*54 + g*9 + k*3 + l
    for (int r = tid; r < RLEN; r += 256) {
        int f = r / 54;  int r1 = r - f * 54;
        int g = r1 / 9;  int r2 = r1 - g * 9;
        int k = r2 / 3;  int l  = r2 - k * 3;
        poseOff[r] = (f * 2 + k) * 14 + (g * 2 + l);
        wOff[r]    = k * 3 + l;
    }
    __syncthreads();

    // per block: 16 ij * 324 r = 5184 outputs = 1296 float4
    float* obase = out + ACTS_OUT + (size_t)bid * 5184;
    for (int idx4 = tid; idx4 < 1296; idx4 += 256) {
        int ij = idx4 / 81;
        int rb = (idx4 - ij * 81) * 4;
        int i = ij >> 2, j = ij & 3;
        const float* Pi = Pl + i * 784;   // + m*196 + po
        const float* Wj = Wl + j * 9;     // + m*36  + wo
        float vv[4];
        #pragma unroll
        for (int e = 0; e < 4; ++e) {
            int r  = rb + e;
            int po = poseOff[r];
            int wo = wOff[r];
            float acc = 0.f;
            #pragma unroll
            for (int m = 0; m < 4; ++m)
                acc += Pi[m * 196 + po] * Wj[m * 36 + wo];
            vv[e] = acc;
        }
        float4 v = make_float4(vv[0], vv[1], vv[2], vv[3]);
        *((float4*)(obase + ij * 324 + rb)) = v;
    }
}

extern "C" void kernel_launch(void* const* d_in, const int* in_sizes, int n_in,
                              void* d_out, int out_size, void* d_ws, size_t ws_size,
                              hipStream_t stream) {
    const float* act   = (const float*)d_in[0];
    const float* poses = (const float*)d_in[1];
    const float* W     = (const float*)d_in[2];
    float* out = (float*)d_out;

    acts_kernel<<<324, 256, 0, stream>>>(act, out);
    v_kernel<<<8192, 256, 0, stream>>>(poses, W, out);
}